// Round 7
// baseline (7201.165 us; speedup 1.0000x reference)
//
#include <hip/hip_runtime.h>
#include <math.h>

// Problem constants (from reference)
#define NROWS 18432
#define IN_DIM 1024
#define HID_DIM 4096
#define OUT_DIM 4096
#define NTN 16   // 4096/256 column tiles (both layers)

typedef __attribute__((ext_vector_type(8))) short bf16x8;
typedef __attribute__((ext_vector_type(4))) float f32x4;

typedef const __attribute__((address_space(1))) char gchar;
typedef __attribute__((address_space(3))) char lchar;

__device__ __forceinline__ unsigned short f2bf(float f) {
    union { float f; unsigned u; } v; v.f = f;
    unsigned r = v.u + 0x7fffu + ((v.u >> 16) & 1u);  // RNE
    return (unsigned short)(r >> 16);
}

__device__ __forceinline__ f32x4 MFMA16(bf16x8 a, bf16x8 b, f32x4 c) {
    return __builtin_amdgcn_mfma_f32_16x16x32_bf16(a, b, c, 0, 0, 0);
}

// ---------------- conversion kernels ----------------

__global__ void cvt_f32_bf16_k(const float4* __restrict__ in, uint4* __restrict__ out, int nvec) {
    int i = blockIdx.x * blockDim.x + threadIdx.x;
    if (i >= nvec) return;
    float4 a = in[2 * i], b = in[2 * i + 1];
    union { unsigned short s[8]; uint4 v; } o;
    o.s[0] = f2bf(a.x); o.s[1] = f2bf(a.y); o.s[2] = f2bf(a.z); o.s[3] = f2bf(a.w);
    o.s[4] = f2bf(b.x); o.s[5] = f2bf(b.y); o.s[6] = f2bf(b.z); o.s[7] = f2bf(b.w);
    out[i] = o.v;
}

// int8 values harness-materialized as int32; exact in bf16
__global__ void cvt_i32_bf16_k(const int4* __restrict__ in, uint4* __restrict__ out, int nvec) {
    int i = blockIdx.x * blockDim.x + threadIdx.x;
    if (i >= nvec) return;
    int4 a = in[2 * i], b = in[2 * i + 1];
    union { unsigned short s[8]; uint4 v; } o;
    o.s[0] = f2bf((float)a.x); o.s[1] = f2bf((float)a.y);
    o.s[2] = f2bf((float)a.z); o.s[3] = f2bf((float)a.w);
    o.s[4] = f2bf((float)b.x); o.s[5] = f2bf((float)b.y);
    o.s[6] = f2bf((float)b.z); o.s[7] = f2bf((float)b.w);
    out[i] = o.v;
}

// ---------------- 256x256 GEMM, BK=32, 2 blocks/CU: C = A[M][K] * B[tile][K]^T ----------------
// 8 waves (2M x 4N), per-wave 128x64 out, 16x16x32 MFMA, double-buffered 64 KB LDS (A/B 8KB x2
// units x2 bufs). 64 KB => TWO blocks per CU (160KB LDS): block A's MFMA window overlaps block
// B's LDS-read window on independent pipes (m114) -- the 128KB/1-block version serialized them.
// T2 swizzle for 64-B rows: byte ^= ((row>>1)&3)<<4 (2-way residual conflict = free, m136).
// T4 counted vmcnt(2): stages are 1 gload/wave units; P0->Au0(t+1) wait v2, P1->Bu0 v2,
// P2->Bu1 no wait, P3->Au1 v2. Every unit lands >=3 phases after issue. Tail drains v0 at P0.
// One barrier per phase (pre-MFMA), T5 setprio, T1 XCD swizzle.
// EPI==0: bf16 gelu(acc*sc+bi); EPI==1: f32 acc*sc+bi. Output row-stride hardcoded 4096.
template<int EPI>
__global__ __launch_bounds__(512, 4)
void gemm8p(const unsigned short* __restrict__ A, const unsigned short* __restrict__ B,
            const float* __restrict__ scale, const float* __restrict__ bias,
            void* __restrict__ Cout, int K) {
    extern __shared__ __align__(16) char sm[];   // 65536 bytes dynamic

    const int tid  = threadIdx.x;
    const int lane = tid & 63;
    const int wid  = tid >> 6;
    const int wm   = wid >> 2, wn = wid & 3;

    // T1: bijective XCD swizzle (m204)
    const int nwg  = gridDim.x;
    const int q    = nwg >> 3, r = nwg & 7;
    const int xcd  = blockIdx.x & 7, bidx = blockIdx.x >> 3;
    const int swz  = xcd * q + (xcd < r ? xcd : r) + bidx;
    const int tm   = swz / NTN, tn = swz % NTN;

    const size_t rowbytes = (size_t)K * 2;
    const char* Ag = (const char*)A + (size_t)tm * 256 * rowbytes;
    const char* Bg = (const char*)B + (size_t)tn * 256 * rowbytes;

    const int l16 = lane & 15;
    const int cg  = (lane >> 4) << 4;   // logical col byte (16-B slot) within 64-B row

    f32x4  acc[8][4] = {};
    bf16x8 af[4], bl[2], bh[2];

    const int NT = K >> 5;

// Stage one 8KB unit (UNIT 0: rows 0-127, 1: rows 128-255) of a 256x32bf16 tile.
// LDS dest linear (1 gload_lds/wave-lane); global source pre-inverse-swizzled (rule 21).
#define STAGE(GB, LB, UNIT, KTB) { \
    const int po_ = ((UNIT) << 13) + (tid << 4); \
    const int r_  = po_ >> 6; \
    const int b_  = (po_ & 63) ^ (((r_ >> 1) & 3) << 4); \
    __builtin_amdgcn_global_load_lds( \
        (gchar*)((GB) + (size_t)r_ * rowbytes + (KTB) + (size_t)b_), \
        (lchar*)((LB) + po_), 16, 0, 0); \
}

// swizzled read address for (row, col-slot cg) in a [256][64B] tile
#define RDA(BUF, ROW) ((BUF) + ((ROW) << 6) + (cg ^ ((((ROW) >> 1) & 3) << 4)))

#define SFENCE __builtin_amdgcn_sched_barrier(0)
#define WAITV2 { SFENCE; asm volatile("s_waitcnt vmcnt(2)"); SFENCE; }
#define WAITV0 { SFENCE; asm volatile("s_waitcnt vmcnt(0)"); SFENCE; }
#define BARR   { SFENCE; __builtin_amdgcn_s_barrier(); SFENCE; }

    // prologue: tile 0 -> buffer 0. Order matches ledger: Au0, Bu0 oldest (drained by v2).
    STAGE(Ag, sm,         0, (size_t)0);
    STAGE(Bg, sm + 16384, 0, (size_t)0);
    STAGE(Bg, sm + 16384, 1, (size_t)0);
    STAGE(Ag, sm,         1, (size_t)0);
    WAITV2; BARR;                          // Au0,Bu0 landed; Bu1,Au1 may fly

    for (int t = 0; t < NT; ++t) {
        char* Al = sm + ((t & 1) << 15);
        char* Bl = Al + 16384;
        char* An = sm + (((t & 1) ^ 1) << 15);
        char* Bn = An + 16384;
        const bool   pf  = (t + 1 < NT);
        const size_t ktb = ((size_t)(t + 1)) << 6;  // (t+1)*32 bf16 = *64 bytes

        // ---- phase 0: read af-lo + bl; stage Au0(t+1) ----
        {
            const int ab = (wm << 6) + l16;
            #pragma unroll
            for (int mm = 0; mm < 4; ++mm) af[mm] = *(const bf16x8*)RDA(Al, ab + mm * 16);
            const int bb = (wn << 5) + l16;
            #pragma unroll
            for (int nn = 0; nn < 2; ++nn) bl[nn] = *(const bf16x8*)RDA(Bl, bb + nn * 16);
            if (pf) { STAGE(Ag, An, 0, ktb); WAITV2; }
            else    { WAITV0; }           // tail: drain (covers Bu1,Au1 of last tile)
            BARR;                          // Bu1(t) landed for phase 1
            __builtin_amdgcn_s_setprio(1);
            #pragma unroll
            for (int mm = 0; mm < 4; ++mm)
                #pragma unroll
                for (int nn = 0; nn < 2; ++nn)
                    acc[mm][nn] = MFMA16(af[mm], bl[nn], acc[mm][nn]);
            __builtin_amdgcn_s_setprio(0);
            SFENCE;                        // no post-MFMA barrier (round-6 win)
        }
        // ---- phase 1: read bh; stage Bu0(t+1) ----
        {
            const int bb = 128 + (wn << 5) + l16;
            #pragma unroll
            for (int nn = 0; nn < 2; ++nn) bh[nn] = *(const bf16x8*)RDA(Bl, bb + nn * 16);
            if (pf) { STAGE(Bg, Bn, 0, ktb); WAITV2; }
            BARR;                          // Au1(t) landed for phase 2
            __builtin_amdgcn_s_setprio(1);
            #pragma unroll
            for (int mm = 0; mm < 4; ++mm)
                #pragma unroll
                for (int nn = 0; nn < 2; ++nn)
                    acc[mm][2 + nn] = MFMA16(af[mm], bh[nn], acc[mm][2 + nn]);
            __builtin_amdgcn_s_setprio(0);
            SFENCE;
        }
        // ---- phase 2: read af-hi; stage Bu1(t+1) ----
        {
            const int ab = 128 + (wm << 6) + l16;
            #pragma unroll
            for (int mm = 0; mm < 4; ++mm) af[mm] = *(const bf16x8*)RDA(Al, ab + mm * 16);
            if (pf) STAGE(Bg, Bn, 1, ktb);
            BARR;                          // phase 3 reads nothing new: no vmcnt
            __builtin_amdgcn_s_setprio(1);
            #pragma unroll
            for (int mm = 0; mm < 4; ++mm)
                #pragma unroll
                for (int nn = 0; nn < 2; ++nn)
                    acc[4 + mm][nn] = MFMA16(af[mm], bl[nn], acc[4 + mm][nn]);
            __builtin_amdgcn_s_setprio(0);
            SFENCE;
        }
        // ---- phase 3: stage Au1(t+1) ----
        {
            if (pf) { STAGE(Ag, An, 1, ktb); WAITV2; }  // Au0,Bu0(t+1) landed for next P0
            BARR;
            __builtin_amdgcn_s_setprio(1);
            #pragma unroll
            for (int mm = 0; mm < 4; ++mm)
                #pragma unroll
                for (int nn = 0; nn < 2; ++nn)
                    acc[4 + mm][2 + nn] = MFMA16(af[mm], bh[nn], acc[4 + mm][2 + nn]);
            __builtin_amdgcn_s_setprio(0);
            SFENCE;
        }
    }
#undef STAGE
#undef RDA
#undef SFENCE
#undef WAITV2
#undef WAITV0
#undef BARR

    // epilogue: C/D frag layout col=lane&15, row=(lane>>4)*4+r  [m89/m91]
    const int rg = (lane >> 4) << 2;
    #pragma unroll
    for (int j = 0; j < 4; ++j) {
        const int col = tn * 256 + ((j >> 1) << 7) + (wn << 5) + ((j & 1) << 4) + l16;
        const float sc = scale[col];
        const float bi = bias[col];
        #pragma unroll
        for (int m = 0; m < 8; ++m) {
            const int row0 = tm * 256 + ((m >> 2) << 7) + (wm << 6) + ((m & 3) << 4) + rg;
            #pragma unroll
            for (int rr = 0; rr < 4; ++rr) {
                float v = acc[m][j][rr] * sc + bi;
                if (EPI == 0) {
                    float g = 0.5f * v * (1.0f + erff(v * 0.70710678118654752f));
                    ((unsigned short*)Cout)[(size_t)(row0 + rr) * 4096 + col] = f2bf(g);
                } else {
                    ((float*)Cout)[(size_t)(row0 + rr) * 4096 + col] = v;
                }
            }
        }
    }
}

extern "C" void kernel_launch(void* const* d_in, const int* in_sizes, int n_in,
                              void* d_out, int out_size, void* d_ws, size_t ws_size,
                              hipStream_t stream) {
    const float* x   = (const float*)d_in[0];
    const int*   w1q = (const int*)d_in[1];
    const float* s1  = (const float*)d_in[2];
    const float* b1  = (const float*)d_in[3];
    const int*   w2q = (const int*)d_in[4];
    const float* s2  = (const float*)d_in[5];
    const float* b2  = (const float*)d_in[6];
    float*       out = (float*)d_out;

    // allow 64 KiB dynamic LDS (idempotent, not a stream op)
    hipFuncSetAttribute((const void*)gemm8p<0>, hipFuncAttributeMaxDynamicSharedMemorySize, 65536);
    hipFuncSetAttribute((const void*)gemm8p<1>, hipFuncAttributeMaxDynamicSharedMemorySize, 65536);

    char* ws = (char*)d_ws;
    const size_t XBF  = (size_t)NROWS   * IN_DIM  * 2;
    const size_t W1BF = (size_t)HID_DIM * IN_DIM  * 2;
    const size_t W2BF = (size_t)OUT_DIM * HID_DIM * 2;
    const size_t FIXED = XBF + W1BF + W2BF;

    unsigned short* xbf  = (unsigned short*)ws;
    unsigned short* w1bf = (unsigned short*)(ws + XBF);
    unsigned short* w2bf = (unsigned short*)(ws + XBF + W1BF);
    unsigned short* hbuf = (unsigned short*)(ws + FIXED);

    {
        int nvx = NROWS * IN_DIM / 8;
        cvt_f32_bf16_k<<<(nvx + 255) / 256, 256, 0, stream>>>((const float4*)x, (uint4*)xbf, nvx);
        int nv1 = HID_DIM * IN_DIM / 8;
        cvt_i32_bf16_k<<<(nv1 + 255) / 256, 256, 0, stream>>>((const int4*)w1q, (uint4*)w1bf, nv1);
        int nv2 = OUT_DIM * HID_DIM / 8;
        cvt_i32_bf16_k<<<(nv2 + 255) / 256, 256, 0, stream>>>((const int4*)w2q, (uint4*)w2bf, nv2);
    }

    // chunk M (multiples of 256) so h fits in remaining workspace
    size_t avail = (ws_size > FIXED) ? (ws_size - FIXED) : 0;
    long rp = (long)(avail / ((size_t)HID_DIM * 2));
    rp = (rp / 256) * 256;
    if (rp > NROWS) rp = NROWS;
    if (rp < 256)   rp = 256;

    for (int r0 = 0; r0 < NROWS; r0 += (int)rp) {
        int rows = (int)(((long)(NROWS - r0) < rp) ? (NROWS - r0) : rp);
        dim3 g(NTN * (rows / 256));
        gemm8p<0><<<g, 512, 65536, stream>>>(xbf + (size_t)r0 * IN_DIM, w1bf, s1, b1,
                                             (void*)hbuf, IN_DIM);
        gemm8p<1><<<g, 512, 65536, stream>>>(hbuf, w2bf, s2, b2,
                                             (void*)(out + (size_t)r0 * OUT_DIM), HID_DIM);
    }
    (void)in_sizes; (void)n_in; (void)out_size;
}

// Round 8
// 882.459 us; speedup vs baseline: 8.1603x; 8.1603x over previous
//
#include <hip/hip_runtime.h>
#include <math.h>

// Problem constants (from reference)
#define NROWS 18432
#define IN_DIM 1024
#define HID_DIM 4096
#define OUT_DIM 4096
#define NTN 16   // 4096/256 column tiles (both layers)

typedef __attribute__((ext_vector_type(8))) short bf16x8;
typedef __attribute__((ext_vector_type(4))) float f32x4;

typedef const __attribute__((address_space(1))) char gchar;
typedef __attribute__((address_space(3))) char lchar;

__device__ __forceinline__ unsigned short f2bf(float f) {
    union { float f; unsigned u; } v; v.f = f;
    unsigned r = v.u + 0x7fffu + ((v.u >> 16) & 1u);  // RNE
    return (unsigned short)(r >> 16);
}

__device__ __forceinline__ f32x4 MFMA16(bf16x8 a, bf16x8 b, f32x4 c) {
    return __builtin_amdgcn_mfma_f32_16x16x32_bf16(a, b, c, 0, 0, 0);
}

// ---------------- conversion kernels ----------------

__global__ void cvt_f32_bf16_k(const float4* __restrict__ in, uint4* __restrict__ out, int nvec) {
    int i = blockIdx.x * blockDim.x + threadIdx.x;
    if (i >= nvec) return;
    float4 a = in[2 * i], b = in[2 * i + 1];
    union { unsigned short s[8]; uint4 v; } o;
    o.s[0] = f2bf(a.x); o.s[1] = f2bf(a.y); o.s[2] = f2bf(a.z); o.s[3] = f2bf(a.w);
    o.s[4] = f2bf(b.x); o.s[5] = f2bf(b.y); o.s[6] = f2bf(b.z); o.s[7] = f2bf(b.w);
    out[i] = o.v;
}

// int8 values harness-materialized as int32; exact in bf16
__global__ void cvt_i32_bf16_k(const int4* __restrict__ in, uint4* __restrict__ out, int nvec) {
    int i = blockIdx.x * blockDim.x + threadIdx.x;
    if (i >= nvec) return;
    int4 a = in[2 * i], b = in[2 * i + 1];
    union { unsigned short s[8]; uint4 v; } o;
    o.s[0] = f2bf((float)a.x); o.s[1] = f2bf((float)a.y);
    o.s[2] = f2bf((float)a.z); o.s[3] = f2bf((float)a.w);
    o.s[4] = f2bf((float)b.x); o.s[5] = f2bf((float)b.y);
    o.s[6] = f2bf((float)b.z); o.s[7] = f2bf((float)b.w);
    out[i] = o.v;
}

// ------------- 256x256 GEMM, BK=32, TRIPLE-buffered LDS, 1 barrier/K-tile -------------
// 8 waves (2M x 4N), per-wave 128x64 out, 16x16x32 MFMA. LDS = 3 x 32KB (A 16K + B 16K).
// Staging runs TWO tiles ahead: tile t's units issued at t-2. Per tile:
//   {vmcnt(4) -> s_barrier -> 12 ds_read_b128 -> 4 global_load_lds(t+2) -> 32 MFMA}
// No barrier between reads and MFMA: compiler software-pipelines within the tile, waves skew
// up to one tile -> MFMA pipe overlaps LDS pipe across the 2 waves/SIMD (the round-4..6
// pre-MFMA barrier forced lockstep read/MFMA windows = serial pipes, MfmaUtil capped ~48%).
// Ledger: per-wave vmcnt + barrier = collective landing. Tile t units: issued t-2; newer at
// tile-t barrier = t+1's 4 units -> vmcnt(4); tail vmcnt(0). WAR: stage(t+2) hits buf(t-1),
// issued after the barrier all waves pass only after t-1 reads were consumed (lgkmcnt dep).
// T2 swizzle (64-B rows): byte ^= ((row>>1)&3)<<4, applied to STAGE source + reads (rule 21).
// EPI==0: bf16 gelu(acc*sc+bi); EPI==1: f32 acc*sc+bi. Output row-stride hardcoded 4096.
template<int EPI>
__global__ __launch_bounds__(512, 2)
void gemm3b(const unsigned short* __restrict__ A, const unsigned short* __restrict__ B,
            const float* __restrict__ scale, const float* __restrict__ bias,
            void* __restrict__ Cout, int K) {
    extern __shared__ __align__(16) char sm[];   // 98304 bytes dynamic (3 x 32KB)

    const int tid  = threadIdx.x;
    const int lane = tid & 63;
    const int wid  = tid >> 6;
    const int wm   = wid >> 2, wn = wid & 3;

    // T1: bijective XCD swizzle (m204)
    const int nwg  = gridDim.x;
    const int q    = nwg >> 3, r = nwg & 7;
    const int xcd  = blockIdx.x & 7, bidx = blockIdx.x >> 3;
    const int swz  = xcd * q + (xcd < r ? xcd : r) + bidx;
    const int tm   = swz / NTN, tn = swz % NTN;

    const size_t rowbytes = (size_t)K * 2;
    const char* Ag = (const char*)A + (size_t)tm * 256 * rowbytes;
    const char* Bg = (const char*)B + (size_t)tn * 256 * rowbytes;

    const int l16 = lane & 15;
    const int cg  = (lane >> 4) << 4;   // 16-B col slot within 64-B row

    f32x4  acc[8][4] = {};
    bf16x8 af[4], ah[4], bl[2], bh[2];

    const int NT = K >> 5;

// Stage one 8KB unit (UNIT 0: rows 0-127, 1: rows 128-255) of a 256x32bf16 half (A or B).
// LDS dest linear (1 gload/thread); global source pre-inverse-swizzled (rule 21).
#define STAGE(GB, LB, UNIT, KTB) { \
    const int po_ = ((UNIT) << 13) + (tid << 4); \
    const int r_  = po_ >> 6; \
    const int b_  = (po_ & 63) ^ (((r_ >> 1) & 3) << 4); \
    __builtin_amdgcn_global_load_lds( \
        (gchar*)((GB) + (size_t)r_ * rowbytes + (KTB) + (size_t)b_), \
        (lchar*)((LB) + po_), 16, 0, 0); \
}

// swizzled read address for (row, col-slot cg) in a [256][64B] half
#define RDA(BUF, ROW) ((BUF) + ((ROW) << 6) + (cg ^ ((((ROW) >> 1) & 3) << 4)))

#define SFENCE __builtin_amdgcn_sched_barrier(0)
#define WAITV4 { SFENCE; asm volatile("s_waitcnt vmcnt(4)"); SFENCE; }
#define WAITV0 { SFENCE; asm volatile("s_waitcnt vmcnt(0)"); SFENCE; }
#define BARR   { SFENCE; __builtin_amdgcn_s_barrier(); SFENCE; }

    // prologue: stage tile 0 -> buf0, tile 1 -> buf1 (8 units outstanding)
    {
        char* b0 = sm;
        STAGE(Ag, b0,         0, (size_t)0); STAGE(Ag, b0,         1, (size_t)0);
        STAGE(Bg, b0 + 16384, 0, (size_t)0); STAGE(Bg, b0 + 16384, 1, (size_t)0);
        char* b1 = sm + 32768;
        STAGE(Ag, b1,         0, (size_t)64); STAGE(Ag, b1,         1, (size_t)64);
        STAGE(Bg, b1 + 16384, 0, (size_t)64); STAGE(Bg, b1 + 16384, 1, (size_t)64);
    }

    for (int t = 0; t < NT; ++t) {
        if (t < NT - 1) { WAITV4; }   // tile t landed (only t+1's 4 units newer)
        else            { WAITV0; }   // tail
        BARR;                          // collective: all waves' units of tile t in LDS

        char* Ab = sm + 32768 * (t % 3);
        char* Bb = Ab + 16384;

        // all 12 ds_read_b128 for this tile (compiler interleaves with MFMAs via lgkmcnt)
        const int ab = (wm << 6) + l16;
        #pragma unroll
        for (int mm = 0; mm < 4; ++mm) {
            af[mm] = *(const bf16x8*)RDA(Ab, ab + mm * 16);
            ah[mm] = *(const bf16x8*)RDA(Ab, 128 + ab + mm * 16);
        }
        const int bb = (wn << 5) + l16;
        #pragma unroll
        for (int nn = 0; nn < 2; ++nn) {
            bl[nn] = *(const bf16x8*)RDA(Bb, bb + nn * 16);
            bh[nn] = *(const bf16x8*)RDA(Bb, 128 + bb + nn * 16);
        }

        // stage tile t+2 into buf[(t+2)%3] (= buf of tile t-1; WAR safe past the barrier)
        if (t + 2 < NT) {
            char* Sb = sm + 32768 * ((t + 2) % 3);
            const size_t ktb = ((size_t)(t + 2)) << 6;  // (t+2)*32 bf16 = *64 bytes
            STAGE(Ag, Sb,         0, ktb); STAGE(Ag, Sb,         1, ktb);
            STAGE(Bg, Sb + 16384, 0, ktb); STAGE(Bg, Sb + 16384, 1, ktb);
        }

        // 32 MFMA, full 128x64 x K=32 contribution
        #pragma unroll
        for (int mm = 0; mm < 4; ++mm)
            #pragma unroll
            for (int nn = 0; nn < 2; ++nn) {
                acc[mm][nn]         = MFMA16(af[mm], bl[nn], acc[mm][nn]);
                acc[mm][2 + nn]     = MFMA16(af[mm], bh[nn], acc[mm][2 + nn]);
                acc[4 + mm][nn]     = MFMA16(ah[mm], bl[nn], acc[4 + mm][nn]);
                acc[4 + mm][2 + nn] = MFMA16(ah[mm], bh[nn], acc[4 + mm][2 + nn]);
            }
    }
#undef STAGE
#undef RDA
#undef SFENCE
#undef WAITV4
#undef WAITV0
#undef BARR

    // epilogue: C/D frag layout col=lane&15, row=(lane>>4)*4+r  [m89/m91]
    const int rg = (lane >> 4) << 2;
    #pragma unroll
    for (int j = 0; j < 4; ++j) {
        const int col = tn * 256 + ((j >> 1) << 7) + (wn << 5) + ((j & 1) << 4) + l16;
        const float sc = scale[col];
        const float bi = bias[col];
        #pragma unroll
        for (int m = 0; m < 8; ++m) {
            const int row0 = tm * 256 + ((m >> 2) << 7) + (wm << 6) + ((m & 3) << 4) + rg;
            #pragma unroll
            for (int rr = 0; rr < 4; ++rr) {
                float v = acc[m][j][rr] * sc + bi;
                if (EPI == 0) {
                    float g = 0.5f * v * (1.0f + erff(v * 0.70710678118654752f));
                    ((unsigned short*)Cout)[(size_t)(row0 + rr) * 4096 + col] = f2bf(g);
                } else {
                    ((float*)Cout)[(size_t)(row0 + rr) * 4096 + col] = v;
                }
            }
        }
    }
}

extern "C" void kernel_launch(void* const* d_in, const int* in_sizes, int n_in,
                              void* d_out, int out_size, void* d_ws, size_t ws_size,
                              hipStream_t stream) {
    const float* x   = (const float*)d_in[0];
    const int*   w1q = (const int*)d_in[1];
    const float* s1  = (const float*)d_in[2];
    const float* b1  = (const float*)d_in[3];
    const int*   w2q = (const int*)d_in[4];
    const float* s2  = (const float*)d_in[5];
    const float* b2  = (const float*)d_in[6];
    float*       out = (float*)d_out;

    // allow 96 KiB dynamic LDS (idempotent, not a stream op)
    hipFuncSetAttribute((const void*)gemm3b<0>, hipFuncAttributeMaxDynamicSharedMemorySize, 98304);
    hipFuncSetAttribute((const void*)gemm3b<1>, hipFuncAttributeMaxDynamicSharedMemorySize, 98304);

    char* ws = (char*)d_ws;
    const size_t XBF  = (size_t)NROWS   * IN_DIM  * 2;
    const size_t W1BF = (size_t)HID_DIM * IN_DIM  * 2;
    const size_t W2BF = (size_t)OUT_DIM * HID_DIM * 2;
    const size_t FIXED = XBF + W1BF + W2BF;

    unsigned short* xbf  = (unsigned short*)ws;
    unsigned short* w1bf = (unsigned short*)(ws + XBF);
    unsigned short* w2bf = (unsigned short*)(ws + XBF + W1BF);
    unsigned short* hbuf = (unsigned short*)(ws + FIXED);

    {
        int nvx = NROWS * IN_DIM / 8;
        cvt_f32_bf16_k<<<(nvx + 255) / 256, 256, 0, stream>>>((const float4*)x, (uint4*)xbf, nvx);
        int nv1 = HID_DIM * IN_DIM / 8;
        cvt_i32_bf16_k<<<(nv1 + 255) / 256, 256, 0, stream>>>((const int4*)w1q, (uint4*)w1bf, nv1);
        int nv2 = OUT_DIM * HID_DIM / 8;
        cvt_i32_bf16_k<<<(nv2 + 255) / 256, 256, 0, stream>>>((const int4*)w2q, (uint4*)w2bf, nv2);
    }

    // chunk M (multiples of 256) so h fits in remaining workspace
    size_t avail = (ws_size > FIXED) ? (ws_size - FIXED) : 0;
    long rp = (long)(avail / ((size_t)HID_DIM * 2));
    rp = (rp / 256) * 256;
    if (rp > NROWS) rp = NROWS;
    if (rp < 256)   rp = 256;

    for (int r0 = 0; r0 < NROWS; r0 += (int)rp) {
        int rows = (int)(((long)(NROWS - r0) < rp) ? (NROWS - r0) : rp);
        dim3 g(NTN * (rows / 256));
        gemm3b<0><<<g, 512, 98304, stream>>>(xbf + (size_t)r0 * IN_DIM, w1bf, s1, b1,
                                             (void*)hbuf, IN_DIM);
        gemm3b<1><<<g, 512, 98304, stream>>>(hbuf, w2bf, s2, b2,
                                             (void*)(out + (size_t)r0 * OUT_DIM), HID_DIM);
    }
    (void)in_sizes; (void)n_in; (void)out_size;
}